// Round 3
// baseline (204.686 us; speedup 1.0000x reference)
//
#include <hip/hip_runtime.h>
#include <math.h>

#define B_  8
#define N_  128
#define T_  256
#define L_  32
#define H_  128
#define TT_ 224   // T - L

typedef float f4 __attribute__((ext_vector_type(4)));

__device__ __forceinline__ float fsig(float x) {
    return __builtin_amdgcn_rcpf(1.0f + __expf(-x));
}
__device__ __forceinline__ float ftanh_(float x) {
    return 1.0f - 2.0f * __builtin_amdgcn_rcpf(1.0f + __expf(2.0f * x));
}

// ---------------------------------------------------------------------------
// Kernel 0: Wsum[n,h] = sum_j W_fc[n,j,h]; bsum[n] = sum_j b_fc[n,j]
// ---------------------------------------------------------------------------
__global__ __launch_bounds__(512)
void k_pre(const float* __restrict__ W_fc, const float* __restrict__ b_fc,
           float* __restrict__ wsum, float* __restrict__ bsum) {
    const int n  = blockIdx.x;
    const int h  = threadIdx.x & 127;
    const int jq = threadIdx.x >> 7;          // 0..3
    const float* W = W_fc + (size_t)n * N_ * H_ + (size_t)jq * 32 * H_;
    float s = 0.f;
    #pragma unroll 8
    for (int j = 0; j < 32; ++j) s += W[j * H_ + h];
    __shared__ float part[4][128];
    __shared__ float bp[2];
    part[jq][h] = s;

    if (threadIdx.x < 128) {
        float bv = b_fc[n * N_ + threadIdx.x];
        #pragma unroll
        for (int off = 32; off > 0; off >>= 1) bv += __shfl_down(bv, off, 64);
        if ((threadIdx.x & 63) == 0) bp[threadIdx.x >> 6] = bv;
    }
    __syncthreads();
    if (threadIdx.x < 128)
        wsum[n * H_ + h] = part[0][h] + part[1][h] + part[2][h] + part[3][h];
    if (threadIdx.x == 0) bsum[n] = bp[0] + bp[1];
}

// ---------------------------------------------------------------------------
// Kernel 1: per (b,n) block. Gates gi,gg,go (gf is dead), activations,
// online reductions into Hd, Dinv, X_hat.
// Weights are asm-pinned into VGPRs: at R1/R2 the scheduler chose an
// 80-VGPR schedule and re-loaded the 96 weight floats from L1 inside the
// grp loop (VALUBusy 78% but only 26% useful-FMA rate). The "+v" asm makes
// rematerialization illegal. x-window is chunked (12 floats live) to keep
// peak pressure ~135 regs, under the (256,3) budget of ~168.
// ---------------------------------------------------------------------------
__global__ __launch_bounds__(256, 3)
void k_main(const float* __restrict__ x, const float* __restrict__ W_ih,
            const float* __restrict__ b_ih, const float* __restrict__ b_hh,
            const float* __restrict__ wsum, const float* __restrict__ bsum,
            float* __restrict__ Hd, float* __restrict__ Dinv,
            float* __restrict__ xhat) {
    const int n   = blockIdx.x;
    const int b   = blockIdx.y;
    const int tid = threadIdx.x;
    const int h    = tid & 127;
    const int tg   = tid >> 7;   // 0 or 1
    const int wid  = tid >> 6;   // 0..3
    const int lane = tid & 63;

    __shared__ float xs[T_];
    __shared__ float xr[TT_];
    __shared__ float bia[3 * H_];
    __shared__ float ws_s[H_];
    __shared__ float xh_w[4][112];
    __shared__ float hd_s[H_];
    __shared__ float red[4];

    // ---- W rows into registers, asm-pinned ----
    const f4* Wi4 = (const f4*)(W_ih + ((size_t)n * 4 * H_ + h)          * L_);
    const f4* Wg4 = (const f4*)(W_ih + ((size_t)n * 4 * H_ + 2 * H_ + h) * L_);
    const f4* Wo4 = (const f4*)(W_ih + ((size_t)n * 4 * H_ + 3 * H_ + h) * L_);
    f4 wi[8], wg[8], wo[8];
    #pragma unroll
    for (int i = 0; i < 8; ++i) { wi[i] = Wi4[i]; wg[i] = Wg4[i]; wo[i] = Wo4[i]; }
    asm volatile("" : "+v"(wi[0]), "+v"(wi[1]), "+v"(wi[2]), "+v"(wi[3]),
                      "+v"(wi[4]), "+v"(wi[5]), "+v"(wi[6]), "+v"(wi[7]));
    asm volatile("" : "+v"(wg[0]), "+v"(wg[1]), "+v"(wg[2]), "+v"(wg[3]),
                      "+v"(wg[4]), "+v"(wg[5]), "+v"(wg[6]), "+v"(wg[7]));
    asm volatile("" : "+v"(wo[0]), "+v"(wo[1]), "+v"(wo[2]), "+v"(wo[3]),
                      "+v"(wo[4]), "+v"(wo[5]), "+v"(wo[6]), "+v"(wo[7]));

    // ---- stage x, biases, wsum ----
    xs[tid] = x[((size_t)b * N_ + n) * T_ + tid];
    {
        const float* bi = b_ih + (size_t)n * 4 * H_;
        const float* bh = b_hh + (size_t)n * 4 * H_;
        if (tid < 128) {
            bia[tid]       = bi[tid]       + bh[tid];        // gi
            bia[256 + tid] = bi[384 + tid] + bh[384 + tid];  // go
        } else {
            bia[tid] = bi[128 + tid] + bh[128 + tid];        // gg
            ws_s[tid - 128] = wsum[n * H_ + (tid - 128)];
        }
    }
    __syncthreads();
    if (tid < TT_) xr[tid] = 1.0f / xs[L_ + tid];
    __syncthreads();

    const float bii = bia[h], bgg = bia[128 + h], boo = bia[256 + h];
    const float wsh = ws_s[h];
    float hd_acc = 0.f;
    const int t0 = tg * 112;

    // ---- main loop: 28 groups of 4 t each; L chunked 4x8 ----
    for (int grp = 0; grp < 28; ++grp) {
        const int tb = t0 + grp * 4;           // multiple of 4 -> aligned b128
        float gi_[4] = {bii, bii, bii, bii};
        float gg_[4] = {bgg, bgg, bgg, bgg};
        float go_[4] = {boo, boo, boo, boo};
        #pragma unroll
        for (int lc = 0; lc < 4; ++lc) {
            const f4 xa = *(const f4*)&xs[tb + 8 * lc];
            const f4 xb = *(const f4*)&xs[tb + 8 * lc + 4];
            const f4 xc = *(const f4*)&xs[tb + 8 * lc + 8];
            float xw[12];
            #pragma unroll
            for (int k = 0; k < 4; ++k) {
                xw[k] = xa[k]; xw[4 + k] = xb[k]; xw[8 + k] = xc[k];
            }
            #pragma unroll
            for (int l = 0; l < 8; ++l) {
                const int la = 8 * lc + l;
                const float wI = wi[la >> 2][la & 3];
                const float wG = wg[la >> 2][la & 3];
                const float wO = wo[la >> 2][la & 3];
                #pragma unroll
                for (int dt = 0; dt < 4; ++dt) {
                    const float xl = xw[l + dt];
                    gi_[dt] = fmaf(xl, wI, gi_[dt]);
                    gg_[dt] = fmaf(xl, wG, gg_[dt]);
                    go_[dt] = fmaf(xl, wO, go_[dt]);
                }
            }
        }
        const f4 xr4 = *(const f4*)&xr[tb];
        #pragma unroll
        for (int dt = 0; dt < 4; ++dt) {
            const float c  = fsig(gi_[dt]) * ftanh_(gg_[dt]);
            const float hh = fsig(go_[dt]) * ftanh_(c);
            hd_acc = fmaf(hh, xr4[dt], hd_acc);
            float p = hh * wsh;
            #pragma unroll
            for (int off = 32; off > 0; off >>= 1) p += __shfl_down(p, off, 64);
            if (lane == 0) xh_w[wid][tb + dt - t0] = p;
        }
    }

    // ---- Hd combine ----
    if (tg == 0) hd_s[h] = hd_acc;
    __syncthreads();
    if (tg == 1) Hd[((size_t)b * N_ + n) * H_ + h] = hd_s[h] + hd_acc;

    // ---- X_hat writeout ----
    if (tid < TT_) {
        const int t = tid;
        const float v = (t < 112) ? (xh_w[0][t] + xh_w[1][t])
                                  : (xh_w[2][t - 112] + xh_w[3][t - 112]);
        xhat[((size_t)b * TT_ + t) * N_ + n] = v + bsum[n] + 1e-6f;
    }

    // ---- Dinv ----
    float dv = (tid < TT_) ? xr[tid] : 0.f;
    #pragma unroll
    for (int off = 32; off > 0; off >>= 1) dv += __shfl_down(dv, off, 64);
    if (lane == 0) red[wid] = dv;
    __syncthreads();
    if (tid == 0) Dinv[b * N_ + n] = red[0] + red[1] + red[2] + red[3];
}

// ---------------------------------------------------------------------------
// Kernel 2: G[b,j,n] = (1/224)*(sum_h W_fc[n,j,h]*Hd[b,n,h] + b_fc[n,j]*Dinv[b,n])
// W_fc row staged through LDS with coalesced global loads (R2 did 512B-strided
// per-lane global reads). Row padded to 33 f4 to soften bank conflicts.
// ---------------------------------------------------------------------------
__global__ __launch_bounds__(256)
void k_g(const float* __restrict__ W_fc, const float* __restrict__ b_fc,
         const float* __restrict__ Hd, const float* __restrict__ Dinv,
         float* __restrict__ G) {
    const int n = blockIdx.x;
    __shared__ f4 wrow[128 * 33];          // 67.6 KB
    __shared__ float hd_s[B_][H_];
    __shared__ float dinv_s[B_];
    __shared__ float pacc[128][B_];

    const f4* Wg = (const f4*)(W_fc + (size_t)n * N_ * H_);   // 4096 f4
    for (int i = threadIdx.x; i < 4096; i += 256) {
        const int j = i >> 5, c = i & 31;
        wrow[j * 33 + c] = Wg[i];
    }
    for (int i = threadIdx.x; i < B_ * H_; i += 256)
        hd_s[i >> 7][i & 127] = Hd[((size_t)(i >> 7) * N_ + n) * H_ + (i & 127)];
    if (threadIdx.x < B_) dinv_s[threadIdx.x] = Dinv[threadIdx.x * N_ + n];
    __syncthreads();

    const int j   = threadIdx.x & 127;
    const int hh2 = threadIdx.x >> 7;   // 0 or 1 (wave-uniform)
    float acc[B_];
    #pragma unroll
    for (int bb = 0; bb < B_; ++bb) acc[bb] = 0.f;
    #pragma unroll
    for (int q = 0; q < 16; ++q) {
        const f4 w = wrow[j * 33 + hh2 * 16 + q];
        const int hb = hh2 * 64 + q * 4;
        #pragma unroll
        for (int bb = 0; bb < B_; ++bb) {
            acc[bb] = fmaf(w[0], hd_s[bb][hb + 0],
                      fmaf(w[1], hd_s[bb][hb + 1],
                      fmaf(w[2], hd_s[bb][hb + 2],
                      fmaf(w[3], hd_s[bb][hb + 3], acc[bb]))));
        }
    }
    if (hh2 == 1) {
        #pragma unroll
        for (int bb = 0; bb < B_; ++bb) pacc[j][bb] = acc[bb];
    }
    __syncthreads();
    if (hh2 == 0) {
        const float bj  = b_fc[n * N_ + j];
        const float inv = 1.0f / 224.0f;
        #pragma unroll
        for (int bb = 0; bb < B_; ++bb)
            G[(size_t)bb * N_ * N_ + (size_t)j * N_ + n] =
                (acc[bb] + pacc[j][bb] + bj * dinv_s[bb]) * inv;
    }
}

// ---------------------------------------------------------------------------
extern "C" void kernel_launch(void* const* d_in, const int* in_sizes, int n_in,
                              void* d_out, int out_size, void* d_ws, size_t ws_size,
                              hipStream_t stream) {
    const float* x    = (const float*)d_in[0];
    const float* W_ih = (const float*)d_in[1];
    const float* b_ih = (const float*)d_in[2];
    const float* b_hh = (const float*)d_in[3];
    const float* W_fc = (const float*)d_in[4];
    const float* b_fc = (const float*)d_in[5];

    float* G    = (float*)d_out;                        // B*N*N = 131072
    float* xhat = (float*)d_out + (size_t)B_ * N_ * N_; // B*TT*N = 229376

    float* wsum = (float*)d_ws;              // 16384
    float* bsum = wsum + N_ * H_;            // 128
    float* Hd   = bsum + N_;                 // 131072
    float* Dinv = Hd + (size_t)B_ * N_ * H_; // 1024

    k_pre<<<dim3(N_), dim3(512), 0, stream>>>(W_fc, b_fc, wsum, bsum);
    k_main<<<dim3(N_, B_), dim3(256), 0, stream>>>(x, W_ih, b_ih, b_hh,
                                                   wsum, bsum, Hd, Dinv, xhat);
    k_g<<<dim3(N_), dim3(256), 0, stream>>>(W_fc, b_fc, Hd, Dinv, G);
}